// Round 1
// baseline (60.433 us; speedup 1.0000x reference)
//
#include <hip/hip_runtime.h>
#include <stdint.h>

// KL pairwise: out[n,m] = ent[n] - sum_d a[n,d]*log(b[m,d])
// N = M = 8192, D = 64, fp32 in/out.
// Strategy: bf16 MFMA GEMM for the cross term (write-BW-bound regime),
// fp32 entropy computed during A-staging.

typedef __attribute__((ext_vector_type(8))) __bf16 bfx8;
typedef __attribute__((ext_vector_type(8))) unsigned short usx8;
typedef __attribute__((ext_vector_type(4))) float fx4;

__device__ __forceinline__ unsigned short f2bf(float x) {
    // round-to-nearest-even fp32 -> bf16 (inputs are positive finite)
    unsigned int u = __float_as_uint(x);
    u += 0x7FFFu + ((u >> 16) & 1u);
    return (unsigned short)(u >> 16);
}

__global__ __launch_bounds__(256)
void kl_kernel(const float* __restrict__ A, const float* __restrict__ B,
               float* __restrict__ out, int Mtot) {
    // LDS tiles: 128 rows x 64 cols bf16, stored as 8x 16B chunks per row,
    // XOR-swizzled: chunk16 index ^= (row & 7)  -> bank-conflict-free ds_read_b128.
    __shared__ unsigned short sa[128 * 64];
    __shared__ unsigned short sb[128 * 64];
    __shared__ float sent[128];

    const int t    = threadIdx.x;
    const int brow = blockIdx.y;   // over N (rows of a / rows of out)
    const int bcol = blockIdx.x;   // over M (rows of b / cols of out)

    const float4* A4 = (const float4*)(A + (size_t)brow * (128 * 64));
    const float4* B4 = (const float4*)(B + (size_t)bcol * (128 * 64));

    // ---- stage A (bf16) + ent (fp32) and B (log -> bf16) into LDS ----
#pragma unroll
    for (int k = 0; k < 4; ++k) {
        int p   = t + k * 256;          // 16B-chunk index: 128 rows * 8 chunks
        int row = p >> 3;
        int c16 = p & 7;
        int dst = row * 8 + (c16 ^ (row & 7));

        float4 f0 = A4[2 * p];
        float4 f1 = A4[2 * p + 1];

        // entropy partial over these 8 elements (fp32, pre-rounding)
        float part = f0.x * __logf(f0.x) + f0.y * __logf(f0.y) +
                     f0.z * __logf(f0.z) + f0.w * __logf(f0.w) +
                     f1.x * __logf(f1.x) + f1.y * __logf(f1.y) +
                     f1.z * __logf(f1.z) + f1.w * __logf(f1.w);
        // the 8 chunks of a row live in 8 consecutive lanes -> 3-step butterfly
        part += __shfl_xor(part, 1);
        part += __shfl_xor(part, 2);
        part += __shfl_xor(part, 4);
        if ((t & 7) == 0) sent[row] = part;

        usx8 va;
        va[0] = f2bf(f0.x); va[1] = f2bf(f0.y); va[2] = f2bf(f0.z); va[3] = f2bf(f0.w);
        va[4] = f2bf(f1.x); va[5] = f2bf(f1.y); va[6] = f2bf(f1.z); va[7] = f2bf(f1.w);
        *(usx8*)&sa[dst * 8] = va;

        float4 g0 = B4[2 * p];
        float4 g1 = B4[2 * p + 1];
        usx8 vb;
        vb[0] = f2bf(__logf(g0.x)); vb[1] = f2bf(__logf(g0.y));
        vb[2] = f2bf(__logf(g0.z)); vb[3] = f2bf(__logf(g0.w));
        vb[4] = f2bf(__logf(g1.x)); vb[5] = f2bf(__logf(g1.y));
        vb[6] = f2bf(__logf(g1.z)); vb[7] = f2bf(__logf(g1.w));
        *(usx8*)&sb[dst * 8] = vb;
    }
    __syncthreads();

    // ---- MFMA: each wave computes a 64x64 sub-tile (4x4 fragments of 16x16) ----
    const int lane = t & 63;
    const int wid  = t >> 6;
    const int wr   = (wid >> 1) * 64;   // wave row offset in tile
    const int wc   = (wid & 1) * 64;    // wave col offset in tile
    const int l15  = lane & 15;
    const int lk   = lane >> 4;

    fx4 acc[4][4] = {};
#pragma unroll
    for (int ks = 0; ks < 2; ++ks) {
        bfx8 af[4], bg[4];
#pragma unroll
        for (int i = 0; i < 4; ++i) {
            int ra = wr + i * 16 + l15;
            int c  = ks * 4 + lk;
            af[i] = *(const bfx8*)&sa[(ra * 8 + (c ^ (ra & 7))) * 8];
            int rb = wc + i * 16 + l15;
            bg[i] = *(const bfx8*)&sb[(rb * 8 + (c ^ (rb & 7))) * 8];
        }
#pragma unroll
        for (int i = 0; i < 4; ++i)
#pragma unroll
            for (int j = 0; j < 4; ++j)
                acc[i][j] = __builtin_amdgcn_mfma_f32_16x16x32_bf16(
                    af[i], bg[j], acc[i][j], 0, 0, 0);
    }

    // ---- epilogue: out = ent[row] - cross ----
    const int r0 = lk * 4;
#pragma unroll
    for (int i = 0; i < 4; ++i) {
#pragma unroll
        for (int q = 0; q < 4; ++q) {
            int rt = wr + i * 16 + r0 + q;       // row within tile
            float e = sent[rt];
            size_t base = ((size_t)brow * 128 + rt) * (size_t)Mtot
                        + (size_t)bcol * 128 + wc + l15;
#pragma unroll
            for (int j = 0; j < 4; ++j)
                out[base + (size_t)j * 16] = e - acc[i][j][q];
        }
    }
}

extern "C" void kernel_launch(void* const* d_in, const int* in_sizes, int n_in,
                              void* d_out, int out_size, void* d_ws, size_t ws_size,
                              hipStream_t stream) {
    const float* a = (const float*)d_in[0];
    const float* b = (const float*)d_in[1];
    float* out = (float*)d_out;

    const int D = 64;
    const int N = in_sizes[0] / D;   // 8192
    const int M = in_sizes[1] / D;   // 8192

    dim3 grid(M / 128, N / 128);
    dim3 block(256);
    hipLaunchKernelGGL(kl_kernel, grid, block, 0, stream, a, b, out, M);
}